// Round 9
// baseline (318.502 us; speedup 1.0000x reference)
//
#include <hip/hip_runtime.h>
#include <hip/hip_bf16.h>

#define D 128
#define CHUNK 8192   // edges per build block

// NOTE: build path packs (dst&255, src) into one uint -> requires N <= 65536.

typedef __attribute__((ext_vector_type(8))) short short8;
typedef __attribute__((ext_vector_type(4))) float floatx4;

// fp32 -> bf16 round-to-nearest-even (bit pattern)
static __device__ inline unsigned int f2bf(float f) {
    unsigned int u = __float_as_uint(f);
    return (u + 0x7FFFu + ((u >> 16) & 1u)) >> 16;
}
static __device__ inline float bflo(unsigned int u) { return __uint_as_float(u << 16); }
static __device__ inline float bfhi(unsigned int u) { return __uint_as_float(u & 0xFFFF0000u); }

// ---------------------------------------------------------------- K0+K1 fused:
// blocks [0,16): swizzle W0/W1 into MFMA B-fragment order (hi/lo bf16 split)
// blocks [16,16+NB): per-chunk dst-bucket histogram
__global__ __launch_bounds__(256) void k01_swz_hist(const float* __restrict__ W0,
                                                    const float* __restrict__ W1,
                                                    short8* __restrict__ whi0, short8* __restrict__ wlo0,
                                                    short8* __restrict__ whi1, short8* __restrict__ wlo1,
                                                    const int* __restrict__ dst,
                                                    int* __restrict__ blockhist, int E_) {
    __shared__ int h[256];
    const int tid = threadIdx.x;
    if (blockIdx.x < 16) {
        int gid = blockIdx.x * 256 + tid; // 0..4095
        const float* W = (gid < 2048) ? W0 : W1;
        short8* whi = (gid < 2048) ? whi0 : whi1;
        short8* wlo = (gid < 2048) ? wlo0 : wlo1;
        int t2 = gid & 2047;
        int t = t2 >> 8, q = (t2 >> 6) & 3, lane = t2 & 63;
        short8 hi, lo;
        #pragma unroll
        for (int j = 0; j < 8; ++j) {
            int k = q * 32 + (lane >> 4) * 8 + j;
            int n = t * 16 + (lane & 15);
            float w = W[k * D + n];
            unsigned int hh = f2bf(w);
            hi[j] = (short)hh;
            lo[j] = (short)f2bf(w - __uint_as_float(hh << 16));
        }
        whi[t2] = hi;
        wlo[t2] = lo;
    } else {
        const int b = blockIdx.x - 16;
        h[tid] = 0;
        __syncthreads();
        const int e0 = b * CHUNK;
        const int e1 = min(E_, e0 + CHUNK);
        for (int e = e0 + tid; e < e1; e += 256)
            atomicAdd(&h[dst[e] >> 8], 1);
        __syncthreads();
        blockhist[b * 256 + tid] = h[tid];
    }
}

// ---------------------------------------------------------------- K2: parallel redundant scan (one block per chunk)
// gbase[b][beta] = bucket_start[beta] + sum_{b'<b} blockhist[b'][beta]
__global__ __launch_bounds__(256) void k2_scan(const int* __restrict__ blockhist,
                                               int* __restrict__ gbase,
                                               int* __restrict__ bucket_offs,
                                               int NB, int NBUK, int E_) {
    __shared__ int s[256];
    const int myb = blockIdx.x, tid = threadIdx.x;
    int total = 0, prefix = 0;
    #pragma unroll 4
    for (int b2 = 0; b2 < NB; ++b2) {
        int t = blockhist[b2 * 256 + tid];
        total += t;
        prefix += (b2 < myb) ? t : 0;
    }
    s[tid] = total;
    __syncthreads();
    #pragma unroll
    for (int off = 1; off < 256; off <<= 1) {
        int x = (tid >= off) ? s[tid - off] : 0;
        __syncthreads();
        s[tid] += x;
        __syncthreads();
    }
    int bstart = s[tid] - total; // exclusive
    gbase[myb * 256 + tid] = bstart + prefix;
    if (myb == 0) {
        if (tid < NBUK) bucket_offs[tid] = bstart;
        if (tid == 0) bucket_offs[NBUK] = E_;
    }
}

// ---------------------------------------------------------------- K3: scatter packed (dstlow8,src) into bucket-major staging
__global__ __launch_bounds__(256) void k3_scatter(const int* __restrict__ dst,
                                                  const int* __restrict__ src,
                                                  const int* __restrict__ gbase,
                                                  unsigned int* __restrict__ buf, int E_) {
    __shared__ int c[256];
    const int b = blockIdx.x, tid = threadIdx.x;
    c[tid] = gbase[b * 256 + tid];
    __syncthreads();
    const int e0 = b * CHUNK;
    const int e1 = min(E_, e0 + CHUNK);
    for (int e = e0 + tid; e < e1; e += 256) {
        int v = dst[e];
        int sdx = src[e];
        int pos = atomicAdd(&c[v >> 8], 1);
        buf[pos] = (unsigned int)sdx | ((unsigned int)(v & 255) << 16);
    }
}

// ---------------------------------------------------------------- K4: per-bucket counting sort (by dst&255) -> col, offs, dinv
__global__ __launch_bounds__(256) void k4_bucket(const unsigned int* __restrict__ buf,
                                                 const int* __restrict__ bucket_offs,
                                                 int* __restrict__ offs,
                                                 float* __restrict__ dinv,
                                                 int* __restrict__ col, int N_, int E_) {
    __shared__ int h[256];
    __shared__ int s[256];
    __shared__ int c[256];
    const int beta = blockIdx.x, tid = threadIdx.x;
    const int start = bucket_offs[beta];
    const int end   = bucket_offs[beta + 1];

    h[tid] = 0;
    __syncthreads();
    for (int e = start + tid; e < end; e += 256)
        atomicAdd(&h[(buf[e] >> 16) & 255], 1);
    __syncthreads();

    int deg = h[tid];
    s[tid] = deg;
    __syncthreads();
    #pragma unroll
    for (int off = 1; off < 256; off <<= 1) {
        int x = (tid >= off) ? s[tid - off] : 0;
        __syncthreads();
        s[tid] += x;
        __syncthreads();
    }
    int excl = s[tid] - deg;

    int v0 = beta * 256 + tid;
    if (v0 < N_) {
        offs[v0] = start + excl;
        dinv[v0] = rsqrtf((float)(deg + 1));
    }
    if (beta == 0 && tid == 0) offs[N_] = E_;
    c[tid] = start + excl;
    __syncthreads();

    for (int e = start + tid; e < end; e += 256) {
        unsigned int p = buf[e];
        int pos = atomicAdd(&c[(p >> 16) & 255], 1);
        col[pos] = (int)(p & 0xFFFFu);
    }
}

// ---------------------------------------------------------------- MFMA GEMM: G(bf16, 2 col-planes) = (A @ W) * dinv[row]
// Plane p holds cols [p*64, p*64+64) of every row as 32 uints (bf16 pairs).
__global__ __launch_bounds__(256) void gemm_mfma(const float* __restrict__ A,
                                                 const short8* __restrict__ whi,
                                                 const short8* __restrict__ wlo,
                                                 const float* __restrict__ dinv,
                                                 unsigned int* __restrict__ Gu, int nrows) {
    __shared__ float tileT[128][65];

    const int tid  = threadIdx.x;
    const int wave = tid >> 6, lane = tid & 63;
    const int m = lane & 15, quad = lane >> 4;
    const int rowInBlk = wave * 16;
    const int arow = min(blockIdx.x * 64 + rowInBlk + m, nrows - 1);
    const float* Ap = A + (size_t)arow * D + quad * 8;

    floatx4 acc[8];
    #pragma unroll
    for (int t = 0; t < 8; ++t) acc[t] = (floatx4){0.f, 0.f, 0.f, 0.f};

    #pragma unroll
    for (int q = 0; q < 4; ++q) {
        float4 a0 = *(const float4*)(Ap + q * 32);
        float4 a1 = *(const float4*)(Ap + q * 32 + 4);
        float av[8] = {a0.x, a0.y, a0.z, a0.w, a1.x, a1.y, a1.z, a1.w};
        short8 ahi, alo;
        #pragma unroll
        for (int j = 0; j < 8; ++j) {
            unsigned int h = f2bf(av[j]);
            ahi[j] = (short)h;
            alo[j] = (short)f2bf(av[j] - __uint_as_float(h << 16));
        }
        #pragma unroll
        for (int t = 0; t < 8; ++t) {
            short8 bh = whi[(t * 4 + q) * 64 + lane];
            short8 bl = wlo[(t * 4 + q) * 64 + lane];
            acc[t] = __builtin_amdgcn_mfma_f32_16x16x32_bf16(ahi, bh, acc[t], 0, 0, 0);
            acc[t] = __builtin_amdgcn_mfma_f32_16x16x32_bf16(alo, bh, acc[t], 0, 0, 0);
            acc[t] = __builtin_amdgcn_mfma_f32_16x16x32_bf16(ahi, bl, acc[t], 0, 0, 0);
        }
    }

    #pragma unroll
    for (int t = 0; t < 8; ++t)
        #pragma unroll
        for (int r = 0; r < 4; ++r)
            tileT[t * 16 + m][rowInBlk + quad * 4 + r] = acc[t][r];
    __syncthreads();

    const int orow = tid >> 2, seg = tid & 3;     // seg -> cols [seg*32, seg*32+32)
    const int grow = blockIdx.x * 64 + orow;
    if (grow < nrows) {
        float s = dinv[grow];
        const int p = seg >> 1;                   // plane
        unsigned int* Gp = Gu + ((size_t)(p * nrows + grow)) * 32 + (seg & 1) * 16;
        #pragma unroll
        for (int i = 0; i < 4; ++i) {
            int c0 = seg * 32 + i * 8;
            uint4 o4;
            o4.x = f2bf(tileT[c0 + 0][orow] * s) | (f2bf(tileT[c0 + 1][orow] * s) << 16);
            o4.y = f2bf(tileT[c0 + 2][orow] * s) | (f2bf(tileT[c0 + 3][orow] * s) << 16);
            o4.z = f2bf(tileT[c0 + 4][orow] * s) | (f2bf(tileT[c0 + 5][orow] * s) << 16);
            o4.w = f2bf(tileT[c0 + 6][orow] * s) | (f2bf(tileT[c0 + 7][orow] * s) << 16);
            ((uint4*)Gp)[i] = o4;
        }
    }
}

// ---------------------------------------------------------------- out[i] = relu(dinv[i]*(sum_j g[j] + g[i]) + b)
// Full wave per node: halves process disjoint 8-edge batches -> 16 gathers in
// flight per wave (2x MLP vs half-wave/node) at same VGPR/occupancy budget.
// Cross-half combine via one __shfl_xor(32). Plane per XCD heuristic retained.
__global__ __launch_bounds__(256) void aggregate_kernel(const unsigned int* __restrict__ Gu,
                                                        const int* __restrict__ offs,
                                                        const int* __restrict__ col,
                                                        const float* __restrict__ dinv,
                                                        const float* __restrict__ bias,
                                                        float* __restrict__ out, int nnodes,
                                                        int ngroups) {
    const int bid   = blockIdx.x;
    const int xcd   = bid & 7;
    const int plane = xcd >> 2;
    const int i     = (bid >> 3) * 4 + (xcd & 3);
    if (i >= ngroups) return;
    const int wave = threadIdx.x >> 6;
    const int lane = threadIdx.x & 63;
    const int half = lane >> 5;
    const int l    = lane & 31;
    const int node = i * 4 + wave;
    if (node >= nnodes) return;
    const unsigned int* P = Gu + (size_t)plane * nnodes * 32;

    float ax = 0.f, ay = 0.f;
    const int s = offs[node];
    const int e = offs[node + 1];

    int base = s;
    for (; base + 16 <= e; base += 16) {
        const int b0 = base + half * 8;
        int j0 = col[b0 + 0], j1 = col[b0 + 1], j2 = col[b0 + 2], j3 = col[b0 + 3];
        int j4 = col[b0 + 4], j5 = col[b0 + 5], j6 = col[b0 + 6], j7 = col[b0 + 7];
        unsigned int u0 = P[(size_t)j0 * 32 + l];
        unsigned int u1 = P[(size_t)j1 * 32 + l];
        unsigned int u2 = P[(size_t)j2 * 32 + l];
        unsigned int u3 = P[(size_t)j3 * 32 + l];
        unsigned int u4 = P[(size_t)j4 * 32 + l];
        unsigned int u5 = P[(size_t)j5 * 32 + l];
        unsigned int u6 = P[(size_t)j6 * 32 + l];
        unsigned int u7 = P[(size_t)j7 * 32 + l];
        ax += ((bflo(u0) + bflo(u1)) + (bflo(u2) + bflo(u3))) +
              ((bflo(u4) + bflo(u5)) + (bflo(u6) + bflo(u7)));
        ay += ((bfhi(u0) + bfhi(u1)) + (bfhi(u2) + bfhi(u3))) +
              ((bfhi(u4) + bfhi(u5)) + (bfhi(u6) + bfhi(u7)));
    }
    for (; base + 2 <= e; base += 2) {
        unsigned int u = P[(size_t)col[base + half] * 32 + l];
        ax += bflo(u);
        ay += bfhi(u);
    }
    if (base < e && half == 0) {
        unsigned int u = P[(size_t)col[base] * 32 + l];
        ax += bflo(u);
        ay += bfhi(u);
    }

    // combine the two halves (lane <-> lane^32)
    ax += __shfl_xor(ax, 32, 64);
    ay += __shfl_xor(ay, 32, 64);

    // self-loop (same value in both halves; harmless to add in both)
    unsigned int su = P[(size_t)node * 32 + l];
    ax += bflo(su);
    ay += bfhi(su);

    if (half == 0) {
        float dv = dinv[node];
        float2 bb = ((const float2*)bias)[plane * 32 + l];
        float2 o;
        o.x = fmaxf(fmaf(dv, ax, bb.x), 0.f);
        o.y = fmaxf(fmaf(dv, ay, bb.y), 0.f);
        ((float2*)out)[(size_t)node * 64 + plane * 32 + l] = o;
    }
}

// ----------------------------------------------------------------
extern "C" void kernel_launch(void* const* d_in, const int* in_sizes, int n_in,
                              void* d_out, int out_size, void* d_ws, size_t ws_size,
                              hipStream_t stream) {
    const float* x    = (const float*)d_in[0];
    const int*   edge = (const int*)d_in[1];
    const float* W0   = (const float*)d_in[2];
    const float* b0   = (const float*)d_in[3];
    const float* W1   = (const float*)d_in[4];
    const float* b1   = (const float*)d_in[5];
    float* out = (float*)d_out;

    const int N_ = in_sizes[0] / D;
    const int E_ = in_sizes[1] / 2;
    const int* srcp = edge;       // edge_index[0]
    const int* dstp = edge + E_;  // edge_index[1]

    const int NB   = (E_ + CHUNK - 1) / CHUNK;
    const int NBUK = (N_ + 255) >> 8;

    char* p = (char*)d_ws;
    auto carve = [&](size_t bytes) { char* q = p; p += (bytes + 255) & ~(size_t)255; return q; };
    int*          blockhist = (int*)          carve((size_t)NB * 256 * 4);
    int*          gbase     = (int*)          carve((size_t)NB * 256 * 4);
    int*          buck_offs = (int*)          carve((size_t)(NBUK + 1) * 4);
    int*          offs      = (int*)          carve((size_t)(N_ + 1) * 4);
    float*        dinv      = (float*)        carve((size_t)N_ * 4);
    unsigned int* buf       = (unsigned int*) carve((size_t)E_ * 4);
    int*          col       = (int*)          carve((size_t)E_ * 4);
    unsigned int* gu        = (unsigned int*) carve((size_t)N_ * 64 * 4); // 2 planes x N x 32 uints
    short8*       whi0      = (short8*)       carve(2048 * 16);
    short8*       wlo0      = (short8*)       carve(2048 * 16);
    short8*       whi1      = (short8*)       carve(2048 * 16);
    short8*       wlo1      = (short8*)       carve(2048 * 16);

    k01_swz_hist<<<16 + NB, 256, 0, stream>>>(W0, W1, whi0, wlo0, whi1, wlo1,
                                              dstp, blockhist, E_);
    k2_scan     <<<NB,      256, 0, stream>>>(blockhist, gbase, buck_offs, NB, NBUK, E_);
    k3_scatter  <<<NB,      256, 0, stream>>>(dstp, srcp, gbase, buf, E_);
    k4_bucket   <<<NBUK,    256, 0, stream>>>(buf, buck_offs, offs, dinv, col, N_, E_);

    const int gmb = (N_ + 63) / 64;
    const int ngroups = (N_ + 3) / 4;               // 4 nodes (waves) per block
    const int agrid   = ((ngroups + 3) / 4) * 8;    // XCD-pinned flat grid (2 planes)

    gemm_mfma       <<<gmb,   256, 0, stream>>>(x, whi0, wlo0, dinv, gu, N_);
    aggregate_kernel<<<agrid, 256, 0, stream>>>(gu, offs, col, dinv, b0, out, N_, ngroups);
    gemm_mfma       <<<gmb,   256, 0, stream>>>(out, whi1, wlo1, dinv, gu, N_);
    aggregate_kernel<<<agrid, 256, 0, stream>>>(gu, offs, col, dinv, b1, out, N_, ngroups);
}

// Round 10
// 272.646 us; speedup vs baseline: 1.1682x; 1.1682x over previous
//
#include <hip/hip_runtime.h>
#include <hip/hip_bf16.h>

#define D 128
#define CHUNK 8192   // edges per build block

// NOTE: build path packs (dst&255, src) into one uint -> requires N <= 65536.

typedef __attribute__((ext_vector_type(8))) short short8;
typedef __attribute__((ext_vector_type(4))) float floatx4;

// fp32 -> bf16 round-to-nearest-even (bit pattern)
static __device__ inline unsigned int f2bf(float f) {
    unsigned int u = __float_as_uint(f);
    return (u + 0x7FFFu + ((u >> 16) & 1u)) >> 16;
}
static __device__ inline float bflo(unsigned int u) { return __uint_as_float(u << 16); }
static __device__ inline float bfhi(unsigned int u) { return __uint_as_float(u & 0xFFFF0000u); }

// ---------------------------------------------------------------- K0+K1 fused:
// blocks [0,16): swizzle W0/W1 into MFMA B-fragment order (hi/lo bf16 split)
// blocks [16,16+NB): per-chunk dst-bucket histogram
__global__ __launch_bounds__(256) void k01_swz_hist(const float* __restrict__ W0,
                                                    const float* __restrict__ W1,
                                                    short8* __restrict__ whi0, short8* __restrict__ wlo0,
                                                    short8* __restrict__ whi1, short8* __restrict__ wlo1,
                                                    const int* __restrict__ dst,
                                                    int* __restrict__ blockhist, int E_) {
    __shared__ int h[256];
    const int tid = threadIdx.x;
    if (blockIdx.x < 16) {
        int gid = blockIdx.x * 256 + tid; // 0..4095
        const float* W = (gid < 2048) ? W0 : W1;
        short8* whi = (gid < 2048) ? whi0 : whi1;
        short8* wlo = (gid < 2048) ? wlo0 : wlo1;
        int t2 = gid & 2047;
        int t = t2 >> 8, q = (t2 >> 6) & 3, lane = t2 & 63;
        short8 hi, lo;
        #pragma unroll
        for (int j = 0; j < 8; ++j) {
            int k = q * 32 + (lane >> 4) * 8 + j;
            int n = t * 16 + (lane & 15);
            float w = W[k * D + n];
            unsigned int hh = f2bf(w);
            hi[j] = (short)hh;
            lo[j] = (short)f2bf(w - __uint_as_float(hh << 16));
        }
        whi[t2] = hi;
        wlo[t2] = lo;
    } else {
        const int b = blockIdx.x - 16;
        h[tid] = 0;
        __syncthreads();
        const int e0 = b * CHUNK;
        const int e1 = min(E_, e0 + CHUNK);
        for (int e = e0 + tid; e < e1; e += 256)
            atomicAdd(&h[dst[e] >> 8], 1);
        __syncthreads();
        blockhist[b * 256 + tid] = h[tid];
    }
}

// ---------------------------------------------------------------- K2: parallel redundant scan (one block per chunk)
// gbase[b][beta] = bucket_start[beta] + sum_{b'<b} blockhist[b'][beta]
__global__ __launch_bounds__(256) void k2_scan(const int* __restrict__ blockhist,
                                               int* __restrict__ gbase,
                                               int* __restrict__ bucket_offs,
                                               int NB, int NBUK, int E_) {
    __shared__ int s[256];
    const int myb = blockIdx.x, tid = threadIdx.x;
    int total = 0, prefix = 0;
    #pragma unroll 4
    for (int b2 = 0; b2 < NB; ++b2) {
        int t = blockhist[b2 * 256 + tid];
        total += t;
        prefix += (b2 < myb) ? t : 0;
    }
    s[tid] = total;
    __syncthreads();
    #pragma unroll
    for (int off = 1; off < 256; off <<= 1) {
        int x = (tid >= off) ? s[tid - off] : 0;
        __syncthreads();
        s[tid] += x;
        __syncthreads();
    }
    int bstart = s[tid] - total; // exclusive
    gbase[myb * 256 + tid] = bstart + prefix;
    if (myb == 0) {
        if (tid < NBUK) bucket_offs[tid] = bstart;
        if (tid == 0) bucket_offs[NBUK] = E_;
    }
}

// ---------------------------------------------------------------- K3: scatter packed (dstlow8,src) into bucket-major staging
__global__ __launch_bounds__(256) void k3_scatter(const int* __restrict__ dst,
                                                  const int* __restrict__ src,
                                                  const int* __restrict__ gbase,
                                                  unsigned int* __restrict__ buf, int E_) {
    __shared__ int c[256];
    const int b = blockIdx.x, tid = threadIdx.x;
    c[tid] = gbase[b * 256 + tid];
    __syncthreads();
    const int e0 = b * CHUNK;
    const int e1 = min(E_, e0 + CHUNK);
    for (int e = e0 + tid; e < e1; e += 256) {
        int v = dst[e];
        int sdx = src[e];
        int pos = atomicAdd(&c[v >> 8], 1);
        buf[pos] = (unsigned int)sdx | ((unsigned int)(v & 255) << 16);
    }
}

// ---------------------------------------------------------------- K4: per-bucket counting sort (by dst&255) -> col, offs, dinv
__global__ __launch_bounds__(256) void k4_bucket(const unsigned int* __restrict__ buf,
                                                 const int* __restrict__ bucket_offs,
                                                 int* __restrict__ offs,
                                                 float* __restrict__ dinv,
                                                 int* __restrict__ col, int N_, int E_) {
    __shared__ int h[256];
    __shared__ int s[256];
    __shared__ int c[256];
    const int beta = blockIdx.x, tid = threadIdx.x;
    const int start = bucket_offs[beta];
    const int end   = bucket_offs[beta + 1];

    h[tid] = 0;
    __syncthreads();
    for (int e = start + tid; e < end; e += 256)
        atomicAdd(&h[(buf[e] >> 16) & 255], 1);
    __syncthreads();

    int deg = h[tid];
    s[tid] = deg;
    __syncthreads();
    #pragma unroll
    for (int off = 1; off < 256; off <<= 1) {
        int x = (tid >= off) ? s[tid - off] : 0;
        __syncthreads();
        s[tid] += x;
        __syncthreads();
    }
    int excl = s[tid] - deg;

    int v0 = beta * 256 + tid;
    if (v0 < N_) {
        offs[v0] = start + excl;
        dinv[v0] = rsqrtf((float)(deg + 1));
    }
    if (beta == 0 && tid == 0) offs[N_] = E_;
    c[tid] = start + excl;
    __syncthreads();

    for (int e = start + tid; e < end; e += 256) {
        unsigned int p = buf[e];
        int pos = atomicAdd(&c[(p >> 16) & 255], 1);
        col[pos] = (int)(p & 0xFFFFu);
    }
}

// ---------------------------------------------------------------- MFMA GEMM: G(bf16, 2 col-planes) = (A @ W) * dinv[row]
// Plane p holds cols [p*64, p*64+64) of every row as 32 uints (bf16 pairs).
__global__ __launch_bounds__(256) void gemm_mfma(const float* __restrict__ A,
                                                 const short8* __restrict__ whi,
                                                 const short8* __restrict__ wlo,
                                                 const float* __restrict__ dinv,
                                                 unsigned int* __restrict__ Gu, int nrows) {
    __shared__ float tileT[128][65];

    const int tid  = threadIdx.x;
    const int wave = tid >> 6, lane = tid & 63;
    const int m = lane & 15, quad = lane >> 4;
    const int rowInBlk = wave * 16;
    const int arow = min(blockIdx.x * 64 + rowInBlk + m, nrows - 1);
    const float* Ap = A + (size_t)arow * D + quad * 8;

    floatx4 acc[8];
    #pragma unroll
    for (int t = 0; t < 8; ++t) acc[t] = (floatx4){0.f, 0.f, 0.f, 0.f};

    #pragma unroll
    for (int q = 0; q < 4; ++q) {
        float4 a0 = *(const float4*)(Ap + q * 32);
        float4 a1 = *(const float4*)(Ap + q * 32 + 4);
        float av[8] = {a0.x, a0.y, a0.z, a0.w, a1.x, a1.y, a1.z, a1.w};
        short8 ahi, alo;
        #pragma unroll
        for (int j = 0; j < 8; ++j) {
            unsigned int h = f2bf(av[j]);
            ahi[j] = (short)h;
            alo[j] = (short)f2bf(av[j] - __uint_as_float(h << 16));
        }
        #pragma unroll
        for (int t = 0; t < 8; ++t) {
            short8 bh = whi[(t * 4 + q) * 64 + lane];
            short8 bl = wlo[(t * 4 + q) * 64 + lane];
            acc[t] = __builtin_amdgcn_mfma_f32_16x16x32_bf16(ahi, bh, acc[t], 0, 0, 0);
            acc[t] = __builtin_amdgcn_mfma_f32_16x16x32_bf16(alo, bh, acc[t], 0, 0, 0);
            acc[t] = __builtin_amdgcn_mfma_f32_16x16x32_bf16(ahi, bl, acc[t], 0, 0, 0);
        }
    }

    #pragma unroll
    for (int t = 0; t < 8; ++t)
        #pragma unroll
        for (int r = 0; r < 4; ++r)
            tileT[t * 16 + m][rowInBlk + quad * 4 + r] = acc[t][r];
    __syncthreads();

    const int orow = tid >> 2, seg = tid & 3;     // seg -> cols [seg*32, seg*32+32)
    const int grow = blockIdx.x * 64 + orow;
    if (grow < nrows) {
        float s = dinv[grow];
        const int p = seg >> 1;                   // plane
        unsigned int* Gp = Gu + ((size_t)(p * nrows + grow)) * 32 + (seg & 1) * 16;
        #pragma unroll
        for (int i = 0; i < 4; ++i) {
            int c0 = seg * 32 + i * 8;
            uint4 o4;
            o4.x = f2bf(tileT[c0 + 0][orow] * s) | (f2bf(tileT[c0 + 1][orow] * s) << 16);
            o4.y = f2bf(tileT[c0 + 2][orow] * s) | (f2bf(tileT[c0 + 3][orow] * s) << 16);
            o4.z = f2bf(tileT[c0 + 4][orow] * s) | (f2bf(tileT[c0 + 5][orow] * s) << 16);
            o4.w = f2bf(tileT[c0 + 6][orow] * s) | (f2bf(tileT[c0 + 7][orow] * s) << 16);
            ((uint4*)Gp)[i] = o4;
        }
    }
}

// ---------------------------------------------------------------- out[i] = relu(dinv[i]*(sum_j g[j] + g[i]) + b)
// R8 structure (half-wave per node, 8 nodes per block) + uniform clamped
// 8-edge batches: no serialized 1-2 edge tail windows. Lanes past the end
// re-load col[e-1]'s row (same cache line) and are masked out of the sum.
__global__ __launch_bounds__(256) void aggregate_kernel(const unsigned int* __restrict__ Gu,
                                                        const int* __restrict__ offs,
                                                        const int* __restrict__ col,
                                                        const float* __restrict__ dinv,
                                                        const float* __restrict__ bias,
                                                        float* __restrict__ out, int nnodes,
                                                        int ngroups) {
    const int bid   = blockIdx.x;
    const int xcd   = bid & 7;
    const int plane = xcd >> 2;
    const int i     = (bid >> 3) * 4 + (xcd & 3);
    if (i >= ngroups) return;
    const int lane = threadIdx.x & 31;
    const int node = i * 8 + (threadIdx.x >> 5);
    if (node >= nnodes) return;
    const unsigned int* P = Gu + (size_t)plane * nnodes * 32;

    unsigned int su = P[(size_t)node * 32 + lane]; // self-loop
    float ax = bflo(su), ay = bfhi(su);

    const int s = offs[node];
    const int e = offs[node + 1];

    for (int base = s; base < e; base += 8) {
        const int e1 = e - 1;
        int i1 = min(base + 1, e1), i2 = min(base + 2, e1), i3 = min(base + 3, e1);
        int i4 = min(base + 4, e1), i5 = min(base + 5, e1), i6 = min(base + 6, e1);
        int i7 = min(base + 7, e1);
        int j0 = col[base], j1 = col[i1], j2 = col[i2], j3 = col[i3];
        int j4 = col[i4],  j5 = col[i5], j6 = col[i6], j7 = col[i7];
        unsigned int u0 = P[(size_t)j0 * 32 + lane];
        unsigned int u1 = P[(size_t)j1 * 32 + lane];
        unsigned int u2 = P[(size_t)j2 * 32 + lane];
        unsigned int u3 = P[(size_t)j3 * 32 + lane];
        unsigned int u4 = P[(size_t)j4 * 32 + lane];
        unsigned int u5 = P[(size_t)j5 * 32 + lane];
        unsigned int u6 = P[(size_t)j6 * 32 + lane];
        unsigned int u7 = P[(size_t)j7 * 32 + lane];
        float x0 = bflo(u0),                              y0 = bfhi(u0);
        float x1 = (base + 1 < e) ? bflo(u1) : 0.f,       y1 = (base + 1 < e) ? bfhi(u1) : 0.f;
        float x2 = (base + 2 < e) ? bflo(u2) : 0.f,       y2 = (base + 2 < e) ? bfhi(u2) : 0.f;
        float x3 = (base + 3 < e) ? bflo(u3) : 0.f,       y3 = (base + 3 < e) ? bfhi(u3) : 0.f;
        float x4 = (base + 4 < e) ? bflo(u4) : 0.f,       y4 = (base + 4 < e) ? bfhi(u4) : 0.f;
        float x5 = (base + 5 < e) ? bflo(u5) : 0.f,       y5 = (base + 5 < e) ? bfhi(u5) : 0.f;
        float x6 = (base + 6 < e) ? bflo(u6) : 0.f,       y6 = (base + 6 < e) ? bfhi(u6) : 0.f;
        float x7 = (base + 7 < e) ? bflo(u7) : 0.f,       y7 = (base + 7 < e) ? bfhi(u7) : 0.f;
        ax += ((x0 + x1) + (x2 + x3)) + ((x4 + x5) + (x6 + x7));
        ay += ((y0 + y1) + (y2 + y3)) + ((y4 + y5) + (y6 + y7));
    }

    float dv = dinv[node];
    float2 bb = ((const float2*)bias)[plane * 32 + lane];
    float2 o;
    o.x = fmaxf(fmaf(dv, ax, bb.x), 0.f);
    o.y = fmaxf(fmaf(dv, ay, bb.y), 0.f);
    ((float2*)out)[(size_t)node * 64 + plane * 32 + lane] = o;
}

// ----------------------------------------------------------------
extern "C" void kernel_launch(void* const* d_in, const int* in_sizes, int n_in,
                              void* d_out, int out_size, void* d_ws, size_t ws_size,
                              hipStream_t stream) {
    const float* x    = (const float*)d_in[0];
    const int*   edge = (const int*)d_in[1];
    const float* W0   = (const float*)d_in[2];
    const float* b0   = (const float*)d_in[3];
    const float* W1   = (const float*)d_in[4];
    const float* b1   = (const float*)d_in[5];
    float* out = (float*)d_out;

    const int N_ = in_sizes[0] / D;
    const int E_ = in_sizes[1] / 2;
    const int* srcp = edge;       // edge_index[0]
    const int* dstp = edge + E_;  // edge_index[1]

    const int NB   = (E_ + CHUNK - 1) / CHUNK;
    const int NBUK = (N_ + 255) >> 8;

    char* p = (char*)d_ws;
    auto carve = [&](size_t bytes) { char* q = p; p += (bytes + 255) & ~(size_t)255; return q; };
    int*          blockhist = (int*)          carve((size_t)NB * 256 * 4);
    int*          gbase     = (int*)          carve((size_t)NB * 256 * 4);
    int*          buck_offs = (int*)          carve((size_t)(NBUK + 1) * 4);
    int*          offs      = (int*)          carve((size_t)(N_ + 1) * 4);
    float*        dinv      = (float*)        carve((size_t)N_ * 4);
    unsigned int* buf       = (unsigned int*) carve((size_t)E_ * 4);
    int*          col       = (int*)          carve((size_t)E_ * 4);
    unsigned int* gu        = (unsigned int*) carve((size_t)N_ * 64 * 4); // 2 planes x N x 32 uints
    short8*       whi0      = (short8*)       carve(2048 * 16);
    short8*       wlo0      = (short8*)       carve(2048 * 16);
    short8*       whi1      = (short8*)       carve(2048 * 16);
    short8*       wlo1      = (short8*)       carve(2048 * 16);

    k01_swz_hist<<<16 + NB, 256, 0, stream>>>(W0, W1, whi0, wlo0, whi1, wlo1,
                                              dstp, blockhist, E_);
    k2_scan     <<<NB,      256, 0, stream>>>(blockhist, gbase, buck_offs, NB, NBUK, E_);
    k3_scatter  <<<NB,      256, 0, stream>>>(dstp, srcp, gbase, buf, E_);
    k4_bucket   <<<NBUK,    256, 0, stream>>>(buf, buck_offs, offs, dinv, col, N_, E_);

    const int gmb = (N_ + 63) / 64;
    const int ngroups = (N_ + 7) / 8;               // 8 nodes (half-waves) per block
    const int agrid   = ((ngroups + 3) / 4) * 8;    // XCD-pinned flat grid (2 planes)

    gemm_mfma       <<<gmb,   256, 0, stream>>>(x, whi0, wlo0, dinv, gu, N_);
    aggregate_kernel<<<agrid, 256, 0, stream>>>(gu, offs, col, dinv, b0, out, N_, ngroups);
    gemm_mfma       <<<gmb,   256, 0, stream>>>(out, whi1, wlo1, dinv, gu, N_);
    aggregate_kernel<<<agrid, 256, 0, stream>>>(gu, offs, col, dinv, b1, out, N_, ngroups);
}

// Round 11
// 259.069 us; speedup vs baseline: 1.2294x; 1.0524x over previous
//
#include <hip/hip_runtime.h>
#include <hip/hip_bf16.h>

#define D 128
#define CHUNK 8192     // edges per build block
#define SPAN_CAP 768   // LDS col-stage capacity (8-node span ~ Poisson(264), sigma~16)

// NOTE: build path packs (dst&255, src) into one uint -> requires N <= 65536.

typedef __attribute__((ext_vector_type(8))) short short8;
typedef __attribute__((ext_vector_type(4))) float floatx4;

// fp32 -> bf16 round-to-nearest-even (bit pattern)
static __device__ inline unsigned int f2bf(float f) {
    unsigned int u = __float_as_uint(f);
    return (u + 0x7FFFu + ((u >> 16) & 1u)) >> 16;
}
static __device__ inline float bflo(unsigned int u) { return __uint_as_float(u << 16); }
static __device__ inline float bfhi(unsigned int u) { return __uint_as_float(u & 0xFFFF0000u); }

// ---------------------------------------------------------------- K0+K1 fused:
// blocks [0,16): swizzle W0/W1 into MFMA B-fragment order (hi/lo bf16 split)
// blocks [16,16+NB): per-chunk dst-bucket histogram
__global__ __launch_bounds__(256) void k01_swz_hist(const float* __restrict__ W0,
                                                    const float* __restrict__ W1,
                                                    short8* __restrict__ whi0, short8* __restrict__ wlo0,
                                                    short8* __restrict__ whi1, short8* __restrict__ wlo1,
                                                    const int* __restrict__ dst,
                                                    int* __restrict__ blockhist, int E_) {
    __shared__ int h[256];
    const int tid = threadIdx.x;
    if (blockIdx.x < 16) {
        int gid = blockIdx.x * 256 + tid; // 0..4095
        const float* W = (gid < 2048) ? W0 : W1;
        short8* whi = (gid < 2048) ? whi0 : whi1;
        short8* wlo = (gid < 2048) ? wlo0 : wlo1;
        int t2 = gid & 2047;
        int t = t2 >> 8, q = (t2 >> 6) & 3, lane = t2 & 63;
        short8 hi, lo;
        #pragma unroll
        for (int j = 0; j < 8; ++j) {
            int k = q * 32 + (lane >> 4) * 8 + j;
            int n = t * 16 + (lane & 15);
            float w = W[k * D + n];
            unsigned int hh = f2bf(w);
            hi[j] = (short)hh;
            lo[j] = (short)f2bf(w - __uint_as_float(hh << 16));
        }
        whi[t2] = hi;
        wlo[t2] = lo;
    } else {
        const int b = blockIdx.x - 16;
        h[tid] = 0;
        __syncthreads();
        const int e0 = b * CHUNK;
        const int e1 = min(E_, e0 + CHUNK);
        for (int e = e0 + tid; e < e1; e += 256)
            atomicAdd(&h[dst[e] >> 8], 1);
        __syncthreads();
        blockhist[b * 256 + tid] = h[tid];
    }
}

// ---------------------------------------------------------------- K2+K3 fused: redundant scan + scatter
// Each block recomputes its own cursor row (bucket_start + own-prefix) from
// blockhist, then scatters its chunk. Block 0 also publishes bucket_offs.
__global__ __launch_bounds__(256) void k23_scan_scatter(const int* __restrict__ blockhist,
                                                        const int* __restrict__ dst,
                                                        const int* __restrict__ src,
                                                        int* __restrict__ bucket_offs,
                                                        unsigned int* __restrict__ buf,
                                                        int NB, int NBUK, int E_) {
    __shared__ int s[256];
    __shared__ int c[256];
    const int myb = blockIdx.x, tid = threadIdx.x;
    int total = 0, prefix = 0;
    #pragma unroll 4
    for (int b2 = 0; b2 < NB; ++b2) {
        int t = blockhist[b2 * 256 + tid];
        total += t;
        prefix += (b2 < myb) ? t : 0;
    }
    s[tid] = total;
    __syncthreads();
    #pragma unroll
    for (int off = 1; off < 256; off <<= 1) {
        int x = (tid >= off) ? s[tid - off] : 0;
        __syncthreads();
        s[tid] += x;
        __syncthreads();
    }
    int bstart = s[tid] - total; // exclusive bucket start
    if (myb == 0) {
        if (tid < NBUK) bucket_offs[tid] = bstart;
        if (tid == 0) bucket_offs[NBUK] = E_;
    }
    c[tid] = bstart + prefix;
    __syncthreads();

    const int e0 = myb * CHUNK;
    const int e1 = min(E_, e0 + CHUNK);
    for (int e = e0 + tid; e < e1; e += 256) {
        int v = dst[e];
        int sdx = src[e];
        int pos = atomicAdd(&c[v >> 8], 1);
        buf[pos] = (unsigned int)sdx | ((unsigned int)(v & 255) << 16);
    }
}

// ---------------------------------------------------------------- K4: per-bucket counting sort (by dst&255) -> col, offs, dinv
__global__ __launch_bounds__(256) void k4_bucket(const unsigned int* __restrict__ buf,
                                                 const int* __restrict__ bucket_offs,
                                                 int* __restrict__ offs,
                                                 float* __restrict__ dinv,
                                                 int* __restrict__ col, int N_, int E_) {
    __shared__ int h[256];
    __shared__ int s[256];
    __shared__ int c[256];
    const int beta = blockIdx.x, tid = threadIdx.x;
    const int start = bucket_offs[beta];
    const int end   = bucket_offs[beta + 1];

    h[tid] = 0;
    __syncthreads();
    for (int e = start + tid; e < end; e += 256)
        atomicAdd(&h[(buf[e] >> 16) & 255], 1);
    __syncthreads();

    int deg = h[tid];
    s[tid] = deg;
    __syncthreads();
    #pragma unroll
    for (int off = 1; off < 256; off <<= 1) {
        int x = (tid >= off) ? s[tid - off] : 0;
        __syncthreads();
        s[tid] += x;
        __syncthreads();
    }
    int excl = s[tid] - deg;

    int v0 = beta * 256 + tid;
    if (v0 < N_) {
        offs[v0] = start + excl;
        dinv[v0] = rsqrtf((float)(deg + 1));
    }
    if (beta == 0 && tid == 0) offs[N_] = E_;
    c[tid] = start + excl;
    __syncthreads();

    for (int e = start + tid; e < end; e += 256) {
        unsigned int p = buf[e];
        int pos = atomicAdd(&c[(p >> 16) & 255], 1);
        col[pos] = (int)(p & 0xFFFFu);
    }
}

// ---------------------------------------------------------------- MFMA GEMM: G(bf16, 2 col-planes) = (A @ W) * dinv[row]
// Plane p holds cols [p*64, p*64+64) of every row as 32 uints (bf16 pairs).
__global__ __launch_bounds__(256) void gemm_mfma(const float* __restrict__ A,
                                                 const short8* __restrict__ whi,
                                                 const short8* __restrict__ wlo,
                                                 const float* __restrict__ dinv,
                                                 unsigned int* __restrict__ Gu, int nrows) {
    __shared__ float tileT[128][65];

    const int tid  = threadIdx.x;
    const int wave = tid >> 6, lane = tid & 63;
    const int m = lane & 15, quad = lane >> 4;
    const int rowInBlk = wave * 16;
    const int arow = min(blockIdx.x * 64 + rowInBlk + m, nrows - 1);
    const float* Ap = A + (size_t)arow * D + quad * 8;

    floatx4 acc[8];
    #pragma unroll
    for (int t = 0; t < 8; ++t) acc[t] = (floatx4){0.f, 0.f, 0.f, 0.f};

    #pragma unroll
    for (int q = 0; q < 4; ++q) {
        float4 a0 = *(const float4*)(Ap + q * 32);
        float4 a1 = *(const float4*)(Ap + q * 32 + 4);
        float av[8] = {a0.x, a0.y, a0.z, a0.w, a1.x, a1.y, a1.z, a1.w};
        short8 ahi, alo;
        #pragma unroll
        for (int j = 0; j < 8; ++j) {
            unsigned int h = f2bf(av[j]);
            ahi[j] = (short)h;
            alo[j] = (short)f2bf(av[j] - __uint_as_float(h << 16));
        }
        #pragma unroll
        for (int t = 0; t < 8; ++t) {
            short8 bh = whi[(t * 4 + q) * 64 + lane];
            short8 bl = wlo[(t * 4 + q) * 64 + lane];
            acc[t] = __builtin_amdgcn_mfma_f32_16x16x32_bf16(ahi, bh, acc[t], 0, 0, 0);
            acc[t] = __builtin_amdgcn_mfma_f32_16x16x32_bf16(alo, bh, acc[t], 0, 0, 0);
            acc[t] = __builtin_amdgcn_mfma_f32_16x16x32_bf16(ahi, bl, acc[t], 0, 0, 0);
        }
    }

    #pragma unroll
    for (int t = 0; t < 8; ++t)
        #pragma unroll
        for (int r = 0; r < 4; ++r)
            tileT[t * 16 + m][rowInBlk + quad * 4 + r] = acc[t][r];
    __syncthreads();

    const int orow = tid >> 2, seg = tid & 3;     // seg -> cols [seg*32, seg*32+32)
    const int grow = blockIdx.x * 64 + orow;
    if (grow < nrows) {
        float s = dinv[grow];
        const int p = seg >> 1;                   // plane
        unsigned int* Gp = Gu + ((size_t)(p * nrows + grow)) * 32 + (seg & 1) * 16;
        #pragma unroll
        for (int i = 0; i < 4; ++i) {
            int c0 = seg * 32 + i * 8;
            uint4 o4;
            o4.x = f2bf(tileT[c0 + 0][orow] * s) | (f2bf(tileT[c0 + 1][orow] * s) << 16);
            o4.y = f2bf(tileT[c0 + 2][orow] * s) | (f2bf(tileT[c0 + 3][orow] * s) << 16);
            o4.z = f2bf(tileT[c0 + 4][orow] * s) | (f2bf(tileT[c0 + 5][orow] * s) << 16);
            o4.w = f2bf(tileT[c0 + 6][orow] * s) | (f2bf(tileT[c0 + 7][orow] * s) << 16);
            ((uint4*)Gp)[i] = o4;
        }
    }
}

// ---------------------------------------------------------------- out[i] = relu(dinv[i]*(sum_j g[j] + g[i]) + b)
// R8 structure (half-wave per node, 8 nodes/block) + LDS-staged col lists:
// the 8 nodes' CSR ranges are contiguous, so one coalesced burst stages all
// their cols -> the per-batch global col-load window is eliminated; each
// batch is ds_read (cheap) -> 8 independent gathers.
__global__ __launch_bounds__(256) void aggregate_kernel(const unsigned int* __restrict__ Gu,
                                                        const int* __restrict__ offs,
                                                        const int* __restrict__ col,
                                                        const float* __restrict__ dinv,
                                                        const float* __restrict__ bias,
                                                        float* __restrict__ out, int nnodes,
                                                        int ngroups) {
    __shared__ int scol[SPAN_CAP];
    __shared__ int soffs[9];
    const int bid   = blockIdx.x;
    const int xcd   = bid & 7;
    const int plane = xcd >> 2;
    const int i     = (bid >> 3) * 4 + (xcd & 3);
    if (i >= ngroups) return;
    const int tid   = threadIdx.x;
    const int node0 = i * 8;

    if (tid < 9) soffs[tid] = offs[min(node0 + tid, nnodes)];
    __syncthreads();
    const int s0   = soffs[0];
    const int span = soffs[8] - s0;
    const bool lds_ok = (span <= SPAN_CAP);
    if (lds_ok) {
        for (int k = tid; k < span; k += 256) scol[k] = col[s0 + k];
    }
    __syncthreads();

    const int lane = tid & 31;
    const int node = node0 + (tid >> 5);
    if (node >= nnodes) return;
    const unsigned int* P = Gu + (size_t)plane * nnodes * 32;

    unsigned int su = P[(size_t)node * 32 + lane]; // self-loop
    float ax = bflo(su), ay = bfhi(su);

    const int s = soffs[tid >> 5];
    const int e = soffs[(tid >> 5) + 1];
    int idx = s;

    if (lds_ok) {
        const int b0 = s - s0;
        int k = 0;
        const int deg = e - s;
        for (; k + 8 <= deg; k += 8) {
            int j0 = scol[b0 + k + 0], j1 = scol[b0 + k + 1], j2 = scol[b0 + k + 2], j3 = scol[b0 + k + 3];
            int j4 = scol[b0 + k + 4], j5 = scol[b0 + k + 5], j6 = scol[b0 + k + 6], j7 = scol[b0 + k + 7];
            unsigned int u0 = P[(size_t)j0 * 32 + lane];
            unsigned int u1 = P[(size_t)j1 * 32 + lane];
            unsigned int u2 = P[(size_t)j2 * 32 + lane];
            unsigned int u3 = P[(size_t)j3 * 32 + lane];
            unsigned int u4 = P[(size_t)j4 * 32 + lane];
            unsigned int u5 = P[(size_t)j5 * 32 + lane];
            unsigned int u6 = P[(size_t)j6 * 32 + lane];
            unsigned int u7 = P[(size_t)j7 * 32 + lane];
            ax += ((bflo(u0) + bflo(u1)) + (bflo(u2) + bflo(u3))) +
                  ((bflo(u4) + bflo(u5)) + (bflo(u6) + bflo(u7)));
            ay += ((bfhi(u0) + bfhi(u1)) + (bfhi(u2) + bfhi(u3))) +
                  ((bfhi(u4) + bfhi(u5)) + (bfhi(u6) + bfhi(u7)));
        }
        for (; k + 4 <= deg; k += 4) {
            int j0 = scol[b0 + k + 0], j1 = scol[b0 + k + 1], j2 = scol[b0 + k + 2], j3 = scol[b0 + k + 3];
            unsigned int u0 = P[(size_t)j0 * 32 + lane];
            unsigned int u1 = P[(size_t)j1 * 32 + lane];
            unsigned int u2 = P[(size_t)j2 * 32 + lane];
            unsigned int u3 = P[(size_t)j3 * 32 + lane];
            ax += (bflo(u0) + bflo(u1)) + (bflo(u2) + bflo(u3));
            ay += (bfhi(u0) + bfhi(u1)) + (bfhi(u2) + bfhi(u3));
        }
        for (; k < deg; ++k) {
            unsigned int u = P[(size_t)scol[b0 + k] * 32 + lane];
            ax += bflo(u);
            ay += bfhi(u);
        }
    } else {
        // fallback (statistically never: span ~ Poisson(264), cap 768)
        for (; idx + 4 <= e; idx += 4) {
            int j0 = col[idx + 0], j1 = col[idx + 1], j2 = col[idx + 2], j3 = col[idx + 3];
            unsigned int u0 = P[(size_t)j0 * 32 + lane];
            unsigned int u1 = P[(size_t)j1 * 32 + lane];
            unsigned int u2 = P[(size_t)j2 * 32 + lane];
            unsigned int u3 = P[(size_t)j3 * 32 + lane];
            ax += (bflo(u0) + bflo(u1)) + (bflo(u2) + bflo(u3));
            ay += (bfhi(u0) + bfhi(u1)) + (bfhi(u2) + bfhi(u3));
        }
        for (; idx < e; ++idx) {
            unsigned int u = P[(size_t)col[idx] * 32 + lane];
            ax += bflo(u);
            ay += bfhi(u);
        }
    }

    float dv = dinv[node];
    float2 bb = ((const float2*)bias)[plane * 32 + lane];
    float2 o;
    o.x = fmaxf(fmaf(dv, ax, bb.x), 0.f);
    o.y = fmaxf(fmaf(dv, ay, bb.y), 0.f);
    ((float2*)out)[(size_t)node * 64 + plane * 32 + lane] = o;
}

// ----------------------------------------------------------------
extern "C" void kernel_launch(void* const* d_in, const int* in_sizes, int n_in,
                              void* d_out, int out_size, void* d_ws, size_t ws_size,
                              hipStream_t stream) {
    const float* x    = (const float*)d_in[0];
    const int*   edge = (const int*)d_in[1];
    const float* W0   = (const float*)d_in[2];
    const float* b0   = (const float*)d_in[3];
    const float* W1   = (const float*)d_in[4];
    const float* b1   = (const float*)d_in[5];
    float* out = (float*)d_out;

    const int N_ = in_sizes[0] / D;
    const int E_ = in_sizes[1] / 2;
    const int* srcp = edge;       // edge_index[0]
    const int* dstp = edge + E_;  // edge_index[1]

    const int NB   = (E_ + CHUNK - 1) / CHUNK;
    const int NBUK = (N_ + 255) >> 8;

    char* p = (char*)d_ws;
    auto carve = [&](size_t bytes) { char* q = p; p += (bytes + 255) & ~(size_t)255; return q; };
    int*          blockhist = (int*)          carve((size_t)NB * 256 * 4);
    int*          buck_offs = (int*)          carve((size_t)(NBUK + 1) * 4);
    int*          offs      = (int*)          carve((size_t)(N_ + 1) * 4);
    float*        dinv      = (float*)        carve((size_t)N_ * 4);
    unsigned int* buf       = (unsigned int*) carve((size_t)E_ * 4);
    int*          col       = (int*)          carve((size_t)E_ * 4);
    unsigned int* gu        = (unsigned int*) carve((size_t)N_ * 64 * 4); // 2 planes x N x 32 uints
    short8*       whi0      = (short8*)       carve(2048 * 16);
    short8*       wlo0      = (short8*)       carve(2048 * 16);
    short8*       whi1      = (short8*)       carve(2048 * 16);
    short8*       wlo1      = (short8*)       carve(2048 * 16);

    k01_swz_hist   <<<16 + NB, 256, 0, stream>>>(W0, W1, whi0, wlo0, whi1, wlo1,
                                                 dstp, blockhist, E_);
    k23_scan_scatter<<<NB,     256, 0, stream>>>(blockhist, dstp, srcp, buck_offs, buf,
                                                 NB, NBUK, E_);
    k4_bucket      <<<NBUK,    256, 0, stream>>>(buf, buck_offs, offs, dinv, col, N_, E_);

    const int gmb = (N_ + 63) / 64;
    const int ngroups = (N_ + 7) / 8;               // 8 nodes (half-waves) per block
    const int agrid   = ((ngroups + 3) / 4) * 8;    // XCD-pinned flat grid (2 planes)

    gemm_mfma       <<<gmb,   256, 0, stream>>>(x, whi0, wlo0, dinv, gu, N_);
    aggregate_kernel<<<agrid, 256, 0, stream>>>(gu, offs, col, dinv, b0, out, N_, ngroups);
    gemm_mfma       <<<gmb,   256, 0, stream>>>(out, whi1, wlo1, dinv, gu, N_);
    aggregate_kernel<<<agrid, 256, 0, stream>>>(gu, offs, col, dinv, b1, out, N_, ngroups);
}